// Round 1
// baseline (1302.756 us; speedup 1.0000x reference)
//
#include <hip/hip_runtime.h>

// Problem sizes (fixed by the reference)
constexpr int NROW  = 4096;   // tokens
constexpr int DIN   = 1024;   // input dim
constexpr int DPROJ = 1024;   // projected dim (32*32)
constexpr float INV_DK = 0.17677669529663687f;  // 1/sqrt(32)

#define TILE_BM 128
#define TILE_BN 128
#define TILE_BK 16
#define LDS_STRIDE 132   // 128 + 4 pad, keeps float4 alignment, breaks write conflicts

// C = alpha * (A @ B) + bias   (A: MxK row-major, B: KxN row-major)
__global__ __launch_bounds__(256) void gemm_nn(
    const float* __restrict__ A, const float* __restrict__ B,
    const float* __restrict__ bias, float* __restrict__ C,
    int M, int N, int Kd, float alpha)
{
  __shared__ float As[TILE_BK][LDS_STRIDE];  // transposed: As[k][m]
  __shared__ float Bs[TILE_BK][LDS_STRIDE];  // direct:     Bs[k][n]
  const int tid = threadIdx.x;
  const int tx = tid & 15, ty = tid >> 4;
  const long bm = (long)blockIdx.y * TILE_BM;
  const long bn = (long)blockIdx.x * TILE_BN;

  float acc[8][8];
#pragma unroll
  for (int i = 0; i < 8; ++i)
#pragma unroll
    for (int j = 0; j < 8; ++j) acc[i][j] = 0.f;

  for (int k0 = 0; k0 < Kd; k0 += TILE_BK) {
    // A tile: 128 rows x 16 k, float4 loads along k, transposed scalar stores
#pragma unroll
    for (int i = 0; i < 2; ++i) {
      int v = tid + i * 256;
      int row = v >> 2, c4 = (v & 3) << 2;
      float4 av = *(const float4*)(A + (bm + row) * (long)Kd + k0 + c4);
      As[c4 + 0][row] = av.x; As[c4 + 1][row] = av.y;
      As[c4 + 2][row] = av.z; As[c4 + 3][row] = av.w;
    }
    // B tile: 16 k-rows x 128 cols, fully coalesced float4, vector LDS store
#pragma unroll
    for (int i = 0; i < 2; ++i) {
      int v = tid + i * 256;
      int kr = v >> 5, c4 = (v & 31) << 2;
      *(float4*)&Bs[kr][c4] = *(const float4*)(B + (long)(k0 + kr) * N + bn + c4);
    }
    __syncthreads();
#pragma unroll
    for (int kk = 0; kk < TILE_BK; ++kk) {
      float a[8], b[8];
      // split 4+4 groups: lane stride 4 floats -> conflict-free ds_read_b128
      *(float4*)&a[0] = *(const float4*)&As[kk][ty * 4];
      *(float4*)&a[4] = *(const float4*)&As[kk][64 + ty * 4];
      *(float4*)&b[0] = *(const float4*)&Bs[kk][tx * 4];
      *(float4*)&b[4] = *(const float4*)&Bs[kk][64 + tx * 4];
#pragma unroll
      for (int i = 0; i < 8; ++i)
#pragma unroll
        for (int j = 0; j < 8; ++j)
          acc[i][j] = fmaf(a[i], b[j], acc[i][j]);
    }
    __syncthreads();
  }

  float bb[8];
  if (bias) {
#pragma unroll
    for (int j = 0; j < 4; ++j) {
      bb[j]     = bias[bn + tx * 4 + j];
      bb[4 + j] = bias[bn + 64 + tx * 4 + j];
    }
  } else {
#pragma unroll
    for (int j = 0; j < 8; ++j) bb[j] = 0.f;
  }
#pragma unroll
  for (int i = 0; i < 8; ++i) {
    long row = bm + ((i < 4) ? (ty * 4 + i) : (64 + ty * 4 + (i - 4)));
    float4 o0, o1;
    o0.x = alpha * acc[i][0] + bb[0]; o0.y = alpha * acc[i][1] + bb[1];
    o0.z = alpha * acc[i][2] + bb[2]; o0.w = alpha * acc[i][3] + bb[3];
    o1.x = alpha * acc[i][4] + bb[4]; o1.y = alpha * acc[i][5] + bb[5];
    o1.z = alpha * acc[i][6] + bb[6]; o1.w = alpha * acc[i][7] + bb[7];
    *(float4*)(C + row * (long)N + bn + tx * 4)      = o0;
    *(float4*)(C + row * (long)N + bn + 64 + tx * 4) = o1;
  }
}

// C = alpha * (A @ B^T)   (A: MxK row-major, B: NxK row-major)
__global__ __launch_bounds__(256) void gemm_nt(
    const float* __restrict__ A, const float* __restrict__ B,
    float* __restrict__ C, int M, int N, int Kd, float alpha)
{
  __shared__ float As[TILE_BK][LDS_STRIDE];
  __shared__ float Bs[TILE_BK][LDS_STRIDE];
  const int tid = threadIdx.x;
  const int tx = tid & 15, ty = tid >> 4;
  const long bm = (long)blockIdx.y * TILE_BM;
  const long bn = (long)blockIdx.x * TILE_BN;

  float acc[8][8];
#pragma unroll
  for (int i = 0; i < 8; ++i)
#pragma unroll
    for (int j = 0; j < 8; ++j) acc[i][j] = 0.f;

  for (int k0 = 0; k0 < Kd; k0 += TILE_BK) {
#pragma unroll
    for (int i = 0; i < 2; ++i) {
      int v = tid + i * 256;
      int row = v >> 2, c4 = (v & 3) << 2;
      float4 av = *(const float4*)(A + (bm + row) * (long)Kd + k0 + c4);
      As[c4 + 0][row] = av.x; As[c4 + 1][row] = av.y;
      As[c4 + 2][row] = av.z; As[c4 + 3][row] = av.w;
    }
#pragma unroll
    for (int i = 0; i < 2; ++i) {
      int v = tid + i * 256;
      int n = v >> 2, c4 = (v & 3) << 2;
      float4 bv = *(const float4*)(B + (bn + n) * (long)Kd + k0 + c4);
      Bs[c4 + 0][n] = bv.x; Bs[c4 + 1][n] = bv.y;
      Bs[c4 + 2][n] = bv.z; Bs[c4 + 3][n] = bv.w;
    }
    __syncthreads();
#pragma unroll
    for (int kk = 0; kk < TILE_BK; ++kk) {
      float a[8], b[8];
      *(float4*)&a[0] = *(const float4*)&As[kk][ty * 4];
      *(float4*)&a[4] = *(const float4*)&As[kk][64 + ty * 4];
      *(float4*)&b[0] = *(const float4*)&Bs[kk][tx * 4];
      *(float4*)&b[4] = *(const float4*)&Bs[kk][64 + tx * 4];
#pragma unroll
      for (int i = 0; i < 8; ++i)
#pragma unroll
        for (int j = 0; j < 8; ++j)
          acc[i][j] = fmaf(a[i], b[j], acc[i][j]);
    }
    __syncthreads();
  }

#pragma unroll
  for (int i = 0; i < 8; ++i) {
    long row = bm + ((i < 4) ? (ty * 4 + i) : (64 + ty * 4 + (i - 4)));
    float4 o0, o1;
    o0.x = alpha * acc[i][0]; o0.y = alpha * acc[i][1];
    o0.z = alpha * acc[i][2]; o0.w = alpha * acc[i][3];
    o1.x = alpha * acc[i][4]; o1.y = alpha * acc[i][5];
    o1.z = alpha * acc[i][6]; o1.w = alpha * acc[i][7];
    *(float4*)(C + row * (long)N + bn + tx * 4)      = o0;
    *(float4*)(C + row * (long)N + bn + 64 + tx * 4) = o1;
  }
}

// In-place row softmax over 4096 columns; one 256-thread block per row.
__global__ __launch_bounds__(256) void softmax_inplace(float* __restrict__ S)
{
  const int tid = threadIdx.x;
  float* p = S + (size_t)blockIdx.x * 4096;
  float4 v[4];
  float mx = -3.402823466e38f;
#pragma unroll
  for (int i = 0; i < 4; ++i) {
    v[i] = *(const float4*)(p + 4 * (tid + i * 256));
    mx = fmaxf(mx, fmaxf(fmaxf(v[i].x, v[i].y), fmaxf(v[i].z, v[i].w)));
  }
#pragma unroll
  for (int off = 32; off >= 1; off >>= 1) mx = fmaxf(mx, __shfl_xor(mx, off));
  __shared__ float redm[4], reds[4];
  if ((tid & 63) == 0) redm[tid >> 6] = mx;
  __syncthreads();
  mx = fmaxf(fmaxf(redm[0], redm[1]), fmaxf(redm[2], redm[3]));

  float sum = 0.f;
#pragma unroll
  for (int i = 0; i < 4; ++i) {
    v[i].x = __expf(v[i].x - mx); v[i].y = __expf(v[i].y - mx);
    v[i].z = __expf(v[i].z - mx); v[i].w = __expf(v[i].w - mx);
    sum += (v[i].x + v[i].y) + (v[i].z + v[i].w);
  }
#pragma unroll
  for (int off = 32; off >= 1; off >>= 1) sum += __shfl_xor(sum, off);
  if ((tid & 63) == 0) reds[tid >> 6] = sum;
  __syncthreads();
  sum = (reds[0] + reds[1]) + (reds[2] + reds[3]);
  float inv = 1.0f / sum;
#pragma unroll
  for (int i = 0; i < 4; ++i) {
    v[i].x *= inv; v[i].y *= inv; v[i].z *= inv; v[i].w *= inv;
    *(float4*)(p + 4 * (tid + i * 256)) = v[i];
  }
}

extern "C" void kernel_launch(void* const* d_in, const int* in_sizes, int n_in,
                              void* d_out, int out_size, void* d_ws, size_t ws_size,
                              hipStream_t stream)
{
  const float* x  = (const float*)d_in[0];
  const float* Wq = (const float*)d_in[1];
  const float* bq = (const float*)d_in[2];
  const float* Wk = (const float*)d_in[3];
  const float* bk = (const float*)d_in[4];
  const float* Wv = (const float*)d_in[5];
  const float* bv = (const float*)d_in[6];

  float* attn_out = (float*)d_out;                       // [4096,1024]
  float* attn_w   = attn_out + (size_t)NROW * DPROJ;     // [4096,4096]

  float* Q = (float*)d_ws;                               // 16 MB
  float* K = Q + (size_t)NROW * DPROJ;                   // 16 MB
  float* V = K + (size_t)NROW * DPROJ;                   // 16 MB

  dim3 blk(256);

  // QKV projections: C = x @ W + b
  dim3 gproj(DPROJ / TILE_BN, NROW / TILE_BM);
  gemm_nn<<<gproj, blk, 0, stream>>>(x, Wq, bq, Q, NROW, DPROJ, DIN, 1.0f);
  gemm_nn<<<gproj, blk, 0, stream>>>(x, Wk, bk, K, NROW, DPROJ, DIN, 1.0f);
  gemm_nn<<<gproj, blk, 0, stream>>>(x, Wv, bv, V, NROW, DPROJ, DIN, 1.0f);

  // scores = Q @ K^T / sqrt(32)  -> directly into attn_weights output region
  dim3 gsc(NROW / TILE_BN, NROW / TILE_BM);
  gemm_nt<<<gsc, blk, 0, stream>>>(Q, K, attn_w, NROW, NROW, DPROJ, INV_DK);

  // softmax rows in place
  softmax_inplace<<<NROW, blk, 0, stream>>>(attn_w);

  // attn_output = attn_weights @ V
  dim3 gpv(DPROJ / TILE_BN, NROW / TILE_BM);
  gemm_nn<<<gpv, blk, 0, stream>>>(attn_w, V, nullptr, attn_out, NROW, DPROJ, NROW, 1.0f);
}

// Round 2
// 300.832 us; speedup vs baseline: 4.3305x; 4.3305x over previous
//
#include <hip/hip_runtime.h>

typedef unsigned short ushort_t;
typedef short short8 __attribute__((ext_vector_type(8)));
typedef float f32x4 __attribute__((ext_vector_type(4)));

constexpr int NROW  = 4096;
constexpr int DIN   = 1024;
constexpr int DPROJ = 1024;
constexpr float INV_DK = 0.17677669529663687f;  // 1/sqrt(32)

__device__ __forceinline__ unsigned short f2bf(float f) {
  union { float f; unsigned int u; } v; v.f = f;
  unsigned int r = v.u + 0x7FFFu + ((v.u >> 16) & 1u);
  return (unsigned short)(r >> 16);
}
__device__ __forceinline__ float bf2f(unsigned short h) {
  union { unsigned int u; float f; } v; v.u = ((unsigned int)h) << 16; return v.f;
}

// ---------------------------------------------------------------------------
// Stage one 128-row x 64-col (bf16) tile into LDS via global_load_lds (16B),
// with the read-side XOR swizzle pre-applied to the GLOBAL source address
// (linear LDS dest + inverse-swizzled source; swizzle = involution).
// LDS layout: lds[row*64 + (kchunk ^ (row&7))*8 + k%8]
// ---------------------------------------------------------------------------
__device__ __forceinline__ void stage_tile(const unsigned short* __restrict__ g,
                                           long row0, long ldK, long k0,
                                           unsigned short* lds_tile, int w, int lane) {
  const int rsub = lane >> 3;                    // row within 8-row block
  const int csw  = ((lane & 7) ^ rsub) * 8;      // swizzled source chunk (ushorts)
#pragma unroll
  for (int it = 0; it < 4; ++it) {
    const int rowblk = w * 32 + it * 8;
    const unsigned short* src = g + (row0 + rowblk + rsub) * ldK + k0 + csw;
    unsigned short* dst = lds_tile + rowblk * 64;  // wave-uniform base
    __builtin_amdgcn_global_load_lds(
        (const __attribute__((address_space(1))) unsigned int*)(const void*)src,
        (__attribute__((address_space(3))) unsigned int*)(void*)dst, 16, 0, 0);
  }
}

// ---------------------------------------------------------------------------
// Tiled MFMA GEMM: C[m][n] = sum_k A[m][k]*B[n][k]  (both operands stored
// row-major with K contiguous; B is "B-transposed" storage).
// SPLIT=1: 3-term split-bf16 (Ah*Bh + Ah*Bl + Al*Bh).
// EPI: 0 = f32 out * alpha; 1 = split-bf16 out + col bias; 3 = bf16 out + row bias
// ---------------------------------------------------------------------------
template<int SPLIT, int EPI>
__global__ __launch_bounds__(256, 2) void mfma_gemm(
    const unsigned short* __restrict__ Ah, const unsigned short* __restrict__ Al,
    const unsigned short* __restrict__ Bh, const unsigned short* __restrict__ Bl,
    const float* __restrict__ bias, float* __restrict__ Cf,
    unsigned short* __restrict__ Coh, unsigned short* __restrict__ Col,
    int M, int N, int K, float alpha)
{
  constexpr int NT = SPLIT ? 4 : 2;
  __shared__ __align__(16) unsigned short lds[NT * 128 * 64];
  const int tid  = threadIdx.x;
  const int w    = tid >> 6, lane = tid & 63;
  const int wr   = w >> 1,   wc   = w & 1;
  const int lrow = lane & 15, lgrp = lane >> 4;
  const long bm = (long)blockIdx.y * 128, bn = (long)blockIdx.x * 128;

  f32x4 acc[4][4] = {};

  for (long k0 = 0; k0 < K; k0 += 64) {
    __syncthreads();
    stage_tile(Ah, bm, K, k0, lds + 0 * 8192, w, lane);
    stage_tile(Bh, bn, K, k0, lds + 1 * 8192, w, lane);
    if constexpr (SPLIT) {
      stage_tile(Al, bm, K, k0, lds + 2 * 8192, w, lane);
      stage_tile(Bl, bn, K, k0, lds + 3 * 8192, w, lane);
    }
    __syncthreads();
#pragma unroll
    for (int s = 0; s < 2; ++s) {
      short8 ah[4], bh[4], al[4], bl[4];
#pragma unroll
      for (int i = 0; i < 4; ++i) {
        const int ra   = wr * 64 + i * 16 + lrow;
        const int offa = ra * 64 + (((s * 4) + lgrp) ^ (ra & 7)) * 8;
        ah[i] = *(const short8*)&lds[0 * 8192 + offa];
        if constexpr (SPLIT) al[i] = *(const short8*)&lds[2 * 8192 + offa];
        const int rb   = wc * 64 + i * 16 + lrow;
        const int offb = rb * 64 + (((s * 4) + lgrp) ^ (rb & 7)) * 8;
        bh[i] = *(const short8*)&lds[1 * 8192 + offb];
        if constexpr (SPLIT) bl[i] = *(const short8*)&lds[3 * 8192 + offb];
      }
#pragma unroll
      for (int i = 0; i < 4; ++i)
#pragma unroll
        for (int j = 0; j < 4; ++j) {
          acc[i][j] = __builtin_amdgcn_mfma_f32_16x16x32_bf16(ah[i], bh[j], acc[i][j], 0, 0, 0);
          if constexpr (SPLIT) {
            acc[i][j] = __builtin_amdgcn_mfma_f32_16x16x32_bf16(ah[i], bl[j], acc[i][j], 0, 0, 0);
            acc[i][j] = __builtin_amdgcn_mfma_f32_16x16x32_bf16(al[i], bh[j], acc[i][j], 0, 0, 0);
          }
        }
    }
  }

  // Epilogue. D frag: row = lgrp*4 + reg, col = lrow (within each 16x16).
#pragma unroll
  for (int i = 0; i < 4; ++i) {
    const long rbase = bm + wr * 64 + i * 16 + lgrp * 4;
#pragma unroll
    for (int j = 0; j < 4; ++j) {
      const long cg = bn + wc * 64 + j * 16 + lrow;
#pragma unroll
      for (int r = 0; r < 4; ++r) {
        const long rg = rbase + r;
        float v = acc[i][j][r];
        if constexpr (EPI == 0) {
          Cf[rg * N + cg] = alpha * v;
        } else if constexpr (EPI == 1) {
          v += bias[cg];
          unsigned short h = f2bf(v);
          Coh[rg * N + cg] = h;
          Col[rg * N + cg] = f2bf(v - bf2f(h));
        } else {  // EPI == 3: bf16 out, row-indexed bias
          v += bias[rg];
          Coh[rg * N + cg] = f2bf(v);
        }
      }
    }
  }
}

// f32 -> (hi, lo) bf16, same layout
__global__ __launch_bounds__(256) void split_rows(const float* __restrict__ in,
    unsigned short* __restrict__ oh, unsigned short* __restrict__ ol, int n4)
{
  int idx = blockIdx.x * 256 + threadIdx.x;
  const int stride = gridDim.x * 256;
  for (; idx < n4; idx += stride) {
    float4 v = ((const float4*)in)[idx];
    ushort4 h, l;
    h.x = f2bf(v.x); l.x = f2bf(v.x - bf2f(h.x));
    h.y = f2bf(v.y); l.y = f2bf(v.y - bf2f(h.y));
    h.z = f2bf(v.z); l.z = f2bf(v.z - bf2f(h.z));
    h.w = f2bf(v.w); l.w = f2bf(v.w - bf2f(h.w));
    ((ushort4*)oh)[idx] = h;
    ((ushort4*)ol)[idx] = l;
  }
}

// W (R x C f32) -> W^T hi/lo bf16 (C x R)
__global__ __launch_bounds__(256) void split_transpose(const float* __restrict__ W,
    unsigned short* __restrict__ oTh, unsigned short* __restrict__ oTl, int R, int C)
{
  __shared__ float t[64][65];
  const int rt = blockIdx.y * 64, ct = blockIdx.x * 64;
  const int r0 = threadIdx.x >> 4, c4 = (threadIdx.x & 15) * 4;
#pragma unroll
  for (int rr = 0; rr < 4; ++rr) {
    const int row = r0 + rr * 16;
    float4 v = *(const float4*)(W + (long)(rt + row) * C + ct + c4);
    t[row][c4 + 0] = v.x; t[row][c4 + 1] = v.y;
    t[row][c4 + 2] = v.z; t[row][c4 + 3] = v.w;
  }
  __syncthreads();
#pragma unroll
  for (int rr = 0; rr < 4; ++rr) {
    const int orow = r0 + rr * 16;  // original column index
    float x0 = t[c4 + 0][orow], x1 = t[c4 + 1][orow];
    float x2 = t[c4 + 2][orow], x3 = t[c4 + 3][orow];
    ushort4 h, l;
    h.x = f2bf(x0); l.x = f2bf(x0 - bf2f(h.x));
    h.y = f2bf(x1); l.y = f2bf(x1 - bf2f(h.y));
    h.z = f2bf(x2); l.z = f2bf(x2 - bf2f(h.z));
    h.w = f2bf(x3); l.w = f2bf(x3 - bf2f(h.w));
    *(ushort4*)(oTh + (long)(ct + orow) * R + rt + c4) = h;
    *(ushort4*)(oTl + (long)(ct + orow) * R + rt + c4) = l;
  }
}

// In-place row softmax over 4096 cols + bf16 copy of the normalized row.
__global__ __launch_bounds__(256) void softmax_p(float* __restrict__ S,
                                                 unsigned short* __restrict__ P)
{
  const int tid = threadIdx.x;
  float* p = S + (size_t)blockIdx.x * 4096;
  unsigned short* pb = P + (size_t)blockIdx.x * 4096;
  float4 v[4];
  float mx = -3.402823466e38f;
#pragma unroll
  for (int i = 0; i < 4; ++i) {
    v[i] = *(const float4*)(p + 4 * (tid + i * 256));
    mx = fmaxf(mx, fmaxf(fmaxf(v[i].x, v[i].y), fmaxf(v[i].z, v[i].w)));
  }
#pragma unroll
  for (int off = 32; off >= 1; off >>= 1) mx = fmaxf(mx, __shfl_xor(mx, off));
  __shared__ float redm[4], reds[4];
  if ((tid & 63) == 0) redm[tid >> 6] = mx;
  __syncthreads();
  mx = fmaxf(fmaxf(redm[0], redm[1]), fmaxf(redm[2], redm[3]));

  float sum = 0.f;
#pragma unroll
  for (int i = 0; i < 4; ++i) {
    v[i].x = __expf(v[i].x - mx); v[i].y = __expf(v[i].y - mx);
    v[i].z = __expf(v[i].z - mx); v[i].w = __expf(v[i].w - mx);
    sum += (v[i].x + v[i].y) + (v[i].z + v[i].w);
  }
#pragma unroll
  for (int off = 32; off >= 1; off >>= 1) sum += __shfl_xor(sum, off);
  if ((tid & 63) == 0) reds[tid >> 6] = sum;
  __syncthreads();
  sum = (reds[0] + reds[1]) + (reds[2] + reds[3]);
  const float inv = 1.0f / sum;
#pragma unroll
  for (int i = 0; i < 4; ++i) {
    v[i].x *= inv; v[i].y *= inv; v[i].z *= inv; v[i].w *= inv;
    *(float4*)(p + 4 * (tid + i * 256)) = v[i];
    ushort4 h;
    h.x = f2bf(v[i].x); h.y = f2bf(v[i].y); h.z = f2bf(v[i].z); h.w = f2bf(v[i].w);
    *(ushort4*)(pb + 4 * (tid + i * 256)) = h;
  }
}

extern "C" void kernel_launch(void* const* d_in, const int* in_sizes, int n_in,
                              void* d_out, int out_size, void* d_ws, size_t ws_size,
                              hipStream_t stream)
{
  const float* x  = (const float*)d_in[0];
  const float* Wq = (const float*)d_in[1];
  const float* bq = (const float*)d_in[2];
  const float* Wk = (const float*)d_in[3];
  const float* bk = (const float*)d_in[4];
  const float* Wv = (const float*)d_in[5];
  const float* bv = (const float*)d_in[6];

  float* attn_out = (float*)d_out;                    // [4096,1024] f32
  float* attn_w   = attn_out + (size_t)NROW * DPROJ;  // [4096,4096] f32

  constexpr size_t MB = 1ull << 20;
  // Scratch inside the not-yet-written attn_w region (64 MB): dead before scores.
  char* sc = (char*)attn_w;
  unsigned short* xh   = (unsigned short*)(sc + 0 * MB);   // 8 MB
  unsigned short* xl   = (unsigned short*)(sc + 8 * MB);   // 8 MB
  unsigned short* WqTh = (unsigned short*)(sc + 16 * MB);  // 2 MB
  unsigned short* WqTl = (unsigned short*)(sc + 18 * MB);
  unsigned short* WkTh = (unsigned short*)(sc + 20 * MB);
  unsigned short* WkTl = (unsigned short*)(sc + 22 * MB);
  unsigned short* WvTh = (unsigned short*)(sc + 24 * MB);
  unsigned short* WvTl = (unsigned short*)(sc + 26 * MB);  // unused by GEMM
  // Workspace (peak 40 MB): VT + Q/K splits; P aliases dead Q/K region.
  char* wsb = (char*)d_ws;
  unsigned short* VT = (unsigned short*)(wsb + 0 * MB);    // [1024,4096] 8 MB
  unsigned short* Qh = (unsigned short*)(wsb + 8 * MB);    // 8 MB each
  unsigned short* Ql = (unsigned short*)(wsb + 16 * MB);
  unsigned short* Kh = (unsigned short*)(wsb + 24 * MB);
  unsigned short* Kl = (unsigned short*)(wsb + 32 * MB);
  unsigned short* P  = (unsigned short*)(wsb + 8 * MB);    // 32 MB, alias Q/K

  dim3 blk(256);

  // 1) converts
  split_rows<<<4096, blk, 0, stream>>>(x, xh, xl, NROW * DIN / 4);
  dim3 gtr(16, 16);
  split_transpose<<<gtr, blk, 0, stream>>>(Wq, WqTh, WqTl, DIN, DPROJ);
  split_transpose<<<gtr, blk, 0, stream>>>(Wk, WkTh, WkTl, DIN, DPROJ);
  split_transpose<<<gtr, blk, 0, stream>>>(Wv, WvTh, WvTl, DIN, DPROJ);

  // 2) V^T = Wv^T @ x^T  (plain bf16): A=WvT [1024][1024], B=x [4096][1024]
  mfma_gemm<0, 3><<<dim3(NROW / 128, DPROJ / 128), blk, 0, stream>>>(
      WvTh, nullptr, xh, nullptr, bv, nullptr, VT, nullptr,
      DPROJ, NROW, DIN, 1.0f);

  // 3) Q = x @ Wq + bq (split in, split-bf16 out)
  mfma_gemm<1, 1><<<dim3(DPROJ / 128, NROW / 128), blk, 0, stream>>>(
      xh, xl, WqTh, WqTl, bq, nullptr, Qh, Ql, NROW, DPROJ, DIN, 1.0f);
  // 4) K = x @ Wk + bk
  mfma_gemm<1, 1><<<dim3(DPROJ / 128, NROW / 128), blk, 0, stream>>>(
      xh, xl, WkTh, WkTl, bk, nullptr, Kh, Kl, NROW, DPROJ, DIN, 1.0f);

  // 5) scores = (Q @ K^T) / sqrt(32) -> attn_w f32 (overwrites convert scratch)
  mfma_gemm<1, 0><<<dim3(NROW / 128, NROW / 128), blk, 0, stream>>>(
      Qh, Ql, Kh, Kl, nullptr, attn_w, nullptr, nullptr,
      NROW, NROW, DPROJ, INV_DK);

  // 6) softmax in place + P bf16
  softmax_p<<<NROW, blk, 0, stream>>>(attn_w, P);

  // 7) attn_out = P @ V : A=P [4096][4096], B=VT [1024][4096]
  mfma_gemm<0, 0><<<dim3(DPROJ / 128, NROW / 128), blk, 0, stream>>>(
      P, nullptr, VT, nullptr, nullptr, attn_out, nullptr, nullptr,
      NROW, DPROJ, NROW, 1.0f);
}

// Round 3
// 275.007 us; speedup vs baseline: 4.7372x; 1.0939x over previous
//
#include <hip/hip_runtime.h>

typedef short short8 __attribute__((ext_vector_type(8)));
typedef float f32x4 __attribute__((ext_vector_type(4)));

constexpr int NROW  = 4096;
constexpr int DIN   = 1024;
constexpr int DPROJ = 1024;
constexpr float INV_DK = 0.17677669529663687f;  // 1/sqrt(32)

__device__ __forceinline__ unsigned short f2bf(float f) {
  union { float f; unsigned int u; } v; v.f = f;
  unsigned int r = v.u + 0x7FFFu + ((v.u >> 16) & 1u);
  return (unsigned short)(r >> 16);
}
__device__ __forceinline__ float bf2f(unsigned short h) {
  union { unsigned int u; float f; } v; v.u = ((unsigned int)h) << 16; return v.f;
}

// ---------------------------------------------------------------------------
// Stage one 128-row x 64-col (bf16) tile into LDS via global_load_lds (16B),
// read-side XOR swizzle pre-applied to the GLOBAL source address
// (linear LDS dest + inverse-swizzled source; swizzle is an involution).
// LDS layout: lds[row*64 + (kchunk ^ (row&7))*8 + k%8]
// ---------------------------------------------------------------------------
__device__ __forceinline__ void stage_tile(const unsigned short* __restrict__ g,
                                           long row0, long ldK, long k0,
                                           unsigned short* lds_tile, int w, int lane) {
  const int rsub = lane >> 3;                    // row within 8-row block
  const int csw  = ((lane & 7) ^ rsub) * 8;      // swizzled source chunk (ushorts)
#pragma unroll
  for (int it = 0; it < 4; ++it) {
    const int rowblk = w * 32 + it * 8;
    const unsigned short* src = g + (row0 + rowblk + rsub) * ldK + k0 + csw;
    unsigned short* dst = lds_tile + rowblk * 64;  // wave-uniform base
    __builtin_amdgcn_global_load_lds(
        (const __attribute__((address_space(1))) unsigned int*)(const void*)src,
        (__attribute__((address_space(3))) unsigned int*)(void*)dst, 16, 0, 0);
  }
}

// ---------------------------------------------------------------------------
// Tiled MFMA GEMM, double-buffered 2-phase: C[m][n] = sum_k A[m][k]*B[n][k]
// (both operands row-major with K contiguous; B is "B-transposed" storage).
// SPLIT=1: 3-term split-bf16 (Ah*Bh + Ah*Bl + Al*Bh).
// EPI: 0 = f32 out * alpha; 1 = split-bf16 out + col bias; 3 = bf16 out + row bias
// ---------------------------------------------------------------------------
template<int SPLIT, int EPI>
__global__ __launch_bounds__(256, SPLIT ? 1 : 2) void mfma_gemm(
    const unsigned short* __restrict__ Ah, const unsigned short* __restrict__ Al,
    const unsigned short* __restrict__ Bh, const unsigned short* __restrict__ Bl,
    const float* __restrict__ bias, float* __restrict__ Cf,
    unsigned short* __restrict__ Coh, unsigned short* __restrict__ Col,
    int M, int N, int K, float alpha)
{
  constexpr int NT = SPLIT ? 4 : 2;
  __shared__ __align__(16) unsigned short lds[2][NT * 8192];
  const int tid  = threadIdx.x;
  const int w    = tid >> 6, lane = tid & 63;
  const int wr   = w >> 1,   wc   = w & 1;
  const int lrow = lane & 15, lgrp = lane >> 4;
  const long bm = (long)blockIdx.y * 128, bn = (long)blockIdx.x * 128;

  f32x4 acc[4][4] = {};

  const int nsteps = K >> 6;

  // Prologue: stage first K-tile into buffer 0.
  stage_tile(Ah, bm, K, 0, &lds[0][0 * 8192], w, lane);
  stage_tile(Bh, bn, K, 0, &lds[0][1 * 8192], w, lane);
  if constexpr (SPLIT) {
    stage_tile(Al, bm, K, 0, &lds[0][2 * 8192], w, lane);
    stage_tile(Bl, bn, K, 0, &lds[0][3 * 8192], w, lane);
  }

  int cur = 0;
  for (int t = 0; t < nsteps; ++t) {
    // One barrier per K-step. Its vmcnt(0) drains loads issued a full
    // compute-phase ago (latency hidden); it also guarantees all waves
    // finished reading the buffer we are about to overwrite.
    __syncthreads();
    if (t + 1 < nsteps) {
      const long k0 = (long)(t + 1) << 6;
      const int nb = cur ^ 1;
      stage_tile(Ah, bm, K, k0, &lds[nb][0 * 8192], w, lane);
      stage_tile(Bh, bn, K, k0, &lds[nb][1 * 8192], w, lane);
      if constexpr (SPLIT) {
        stage_tile(Al, bm, K, k0, &lds[nb][2 * 8192], w, lane);
        stage_tile(Bl, bn, K, k0, &lds[nb][3 * 8192], w, lane);
      }
    }
    const unsigned short* L = lds[cur];
#pragma unroll
    for (int s = 0; s < 2; ++s) {
      short8 ah[4], bh[4], al[4], bl[4];
#pragma unroll
      for (int i = 0; i < 4; ++i) {
        const int ra   = wr * 64 + i * 16 + lrow;
        const int offa = ra * 64 + (((s * 4) + lgrp) ^ (ra & 7)) * 8;
        ah[i] = *(const short8*)&L[0 * 8192 + offa];
        if constexpr (SPLIT) al[i] = *(const short8*)&L[2 * 8192 + offa];
        const int rb   = wc * 64 + i * 16 + lrow;
        const int offb = rb * 64 + (((s * 4) + lgrp) ^ (rb & 7)) * 8;
        bh[i] = *(const short8*)&L[1 * 8192 + offb];
        if constexpr (SPLIT) bl[i] = *(const short8*)&L[3 * 8192 + offb];
      }
#pragma unroll
      for (int i = 0; i < 4; ++i)
#pragma unroll
        for (int j = 0; j < 4; ++j) {
          acc[i][j] = __builtin_amdgcn_mfma_f32_16x16x32_bf16(ah[i], bh[j], acc[i][j], 0, 0, 0);
          if constexpr (SPLIT) {
            acc[i][j] = __builtin_amdgcn_mfma_f32_16x16x32_bf16(ah[i], bl[j], acc[i][j], 0, 0, 0);
            acc[i][j] = __builtin_amdgcn_mfma_f32_16x16x32_bf16(al[i], bh[j], acc[i][j], 0, 0, 0);
          }
        }
    }
    cur ^= 1;
  }

  // Epilogue. D frag: row = lgrp*4 + reg, col = lrow (within each 16x16).
#pragma unroll
  for (int i = 0; i < 4; ++i) {
    const long rbase = bm + wr * 64 + i * 16 + lgrp * 4;
#pragma unroll
    for (int j = 0; j < 4; ++j) {
      const long cg = bn + wc * 64 + j * 16 + lrow;
#pragma unroll
      for (int r = 0; r < 4; ++r) {
        const long rg = rbase + r;
        float v = acc[i][j][r];
        if constexpr (EPI == 0) {
          Cf[rg * N + cg] = alpha * v;
        } else if constexpr (EPI == 1) {
          v += bias[cg];
          unsigned short h = f2bf(v);
          Coh[rg * N + cg] = h;
          Col[rg * N + cg] = f2bf(v - bf2f(h));
        } else {  // EPI == 3: bf16 out, row-indexed bias
          v += bias[rg];
          Coh[rg * N + cg] = f2bf(v);
        }
      }
    }
  }
}

// f32 -> (hi, lo) bf16, same layout
__global__ __launch_bounds__(256) void split_rows(const float* __restrict__ in,
    unsigned short* __restrict__ oh, unsigned short* __restrict__ ol, int n4)
{
  int idx = blockIdx.x * 256 + threadIdx.x;
  const int stride = gridDim.x * 256;
  for (; idx < n4; idx += stride) {
    float4 v = ((const float4*)in)[idx];
    ushort4 h, l;
    h.x = f2bf(v.x); l.x = f2bf(v.x - bf2f(h.x));
    h.y = f2bf(v.y); l.y = f2bf(v.y - bf2f(h.y));
    h.z = f2bf(v.z); l.z = f2bf(v.z - bf2f(h.z));
    h.w = f2bf(v.w); l.w = f2bf(v.w - bf2f(h.w));
    ((ushort4*)oh)[idx] = h;
    ((ushort4*)ol)[idx] = l;
  }
}

// W (R x C f32) -> W^T hi/lo bf16 (C x R)
__global__ __launch_bounds__(256) void split_transpose(const float* __restrict__ W,
    unsigned short* __restrict__ oTh, unsigned short* __restrict__ oTl, int R, int C)
{
  __shared__ float t[64][65];
  const int rt = blockIdx.y * 64, ct = blockIdx.x * 64;
  const int r0 = threadIdx.x >> 4, c4 = (threadIdx.x & 15) * 4;
#pragma unroll
  for (int rr = 0; rr < 4; ++rr) {
    const int row = r0 + rr * 16;
    float4 v = *(const float4*)(W + (long)(rt + row) * C + ct + c4);
    t[row][c4 + 0] = v.x; t[row][c4 + 1] = v.y;
    t[row][c4 + 2] = v.z; t[row][c4 + 3] = v.w;
  }
  __syncthreads();
#pragma unroll
  for (int rr = 0; rr < 4; ++rr) {
    const int orow = r0 + rr * 16;  // original column index
    float x0 = t[c4 + 0][orow], x1 = t[c4 + 1][orow];
    float x2 = t[c4 + 2][orow], x3 = t[c4 + 3][orow];
    ushort4 h, l;
    h.x = f2bf(x0); l.x = f2bf(x0 - bf2f(h.x));
    h.y = f2bf(x1); l.y = f2bf(x1 - bf2f(h.y));
    h.z = f2bf(x2); l.z = f2bf(x2 - bf2f(h.z));
    h.w = f2bf(x3); l.w = f2bf(x3 - bf2f(h.w));
    *(ushort4*)(oTh + (long)(ct + orow) * R + rt + c4) = h;
    *(ushort4*)(oTl + (long)(ct + orow) * R + rt + c4) = l;
  }
}

// In-place row softmax over 4096 cols + bf16 copy of the normalized row.
__global__ __launch_bounds__(256) void softmax_p(float* __restrict__ S,
                                                 unsigned short* __restrict__ P)
{
  const int tid = threadIdx.x;
  float* p = S + (size_t)blockIdx.x * 4096;
  unsigned short* pb = P + (size_t)blockIdx.x * 4096;
  float4 v[4];
  float mx = -3.402823466e38f;
#pragma unroll
  for (int i = 0; i < 4; ++i) {
    v[i] = *(const float4*)(p + 4 * (tid + i * 256));
    mx = fmaxf(mx, fmaxf(fmaxf(v[i].x, v[i].y), fmaxf(v[i].z, v[i].w)));
  }
#pragma unroll
  for (int off = 32; off >= 1; off >>= 1) mx = fmaxf(mx, __shfl_xor(mx, off));
  __shared__ float redm[4], reds[4];
  if ((tid & 63) == 0) redm[tid >> 6] = mx;
  __syncthreads();
  mx = fmaxf(fmaxf(redm[0], redm[1]), fmaxf(redm[2], redm[3]));

  float sum = 0.f;
#pragma unroll
  for (int i = 0; i < 4; ++i) {
    v[i].x = __expf(v[i].x - mx); v[i].y = __expf(v[i].y - mx);
    v[i].z = __expf(v[i].z - mx); v[i].w = __expf(v[i].w - mx);
    sum += (v[i].x + v[i].y) + (v[i].z + v[i].w);
  }
#pragma unroll
  for (int off = 32; off >= 1; off >>= 1) sum += __shfl_xor(sum, off);
  if ((tid & 63) == 0) reds[tid >> 6] = sum;
  __syncthreads();
  sum = (reds[0] + reds[1]) + (reds[2] + reds[3]);
  const float inv = 1.0f / sum;
#pragma unroll
  for (int i = 0; i < 4; ++i) {
    v[i].x *= inv; v[i].y *= inv; v[i].z *= inv; v[i].w *= inv;
    *(float4*)(p + 4 * (tid + i * 256)) = v[i];
    ushort4 h;
    h.x = f2bf(v[i].x); h.y = f2bf(v[i].y); h.z = f2bf(v[i].z); h.w = f2bf(v[i].w);
    *(ushort4*)(pb + 4 * (tid + i * 256)) = h;
  }
}

extern "C" void kernel_launch(void* const* d_in, const int* in_sizes, int n_in,
                              void* d_out, int out_size, void* d_ws, size_t ws_size,
                              hipStream_t stream)
{
  const float* x  = (const float*)d_in[0];
  const float* Wq = (const float*)d_in[1];
  const float* bq = (const float*)d_in[2];
  const float* Wk = (const float*)d_in[3];
  const float* bk = (const float*)d_in[4];
  const float* Wv = (const float*)d_in[5];
  const float* bv = (const float*)d_in[6];

  float* attn_out = (float*)d_out;                    // [4096,1024] f32
  float* attn_w   = attn_out + (size_t)NROW * DPROJ;  // [4096,4096] f32

  constexpr size_t MB = 1ull << 20;
  // Scratch inside the not-yet-written attn_w region (64 MB): dead before scores.
  char* sc = (char*)attn_w;
  unsigned short* xh   = (unsigned short*)(sc + 0 * MB);   // 8 MB
  unsigned short* xl   = (unsigned short*)(sc + 8 * MB);   // 8 MB
  unsigned short* WqTh = (unsigned short*)(sc + 16 * MB);  // 2 MB
  unsigned short* WqTl = (unsigned short*)(sc + 18 * MB);
  unsigned short* WkTh = (unsigned short*)(sc + 20 * MB);
  unsigned short* WkTl = (unsigned short*)(sc + 22 * MB);
  unsigned short* WvTh = (unsigned short*)(sc + 24 * MB);
  unsigned short* WvTl = (unsigned short*)(sc + 26 * MB);  // unused by GEMM
  // Workspace (peak 40 MB): VT + Q/K splits; P aliases dead Q/K region.
  char* wsb = (char*)d_ws;
  unsigned short* VT = (unsigned short*)(wsb + 0 * MB);    // [1024,4096] 8 MB
  unsigned short* Qh = (unsigned short*)(wsb + 8 * MB);    // 8 MB each
  unsigned short* Ql = (unsigned short*)(wsb + 16 * MB);
  unsigned short* Kh = (unsigned short*)(wsb + 24 * MB);
  unsigned short* Kl = (unsigned short*)(wsb + 32 * MB);
  unsigned short* P  = (unsigned short*)(wsb + 8 * MB);    // 32 MB, alias Q/K

  dim3 blk(256);

  // 1) converts
  split_rows<<<4096, blk, 0, stream>>>(x, xh, xl, NROW * DIN / 4);
  dim3 gtr(16, 16);
  split_transpose<<<gtr, blk, 0, stream>>>(Wq, WqTh, WqTl, DIN, DPROJ);
  split_transpose<<<gtr, blk, 0, stream>>>(Wk, WkTh, WkTl, DIN, DPROJ);
  split_transpose<<<gtr, blk, 0, stream>>>(Wv, WvTh, WvTl, DIN, DPROJ);

  // 2) V^T = Wv^T @ x^T  (plain bf16): A=WvT [1024][1024], B=x [4096][1024]
  mfma_gemm<0, 3><<<dim3(NROW / 128, DPROJ / 128), blk, 0, stream>>>(
      WvTh, nullptr, xh, nullptr, bv, nullptr, VT, nullptr,
      DPROJ, NROW, DIN, 1.0f);

  // 3) Q = x @ Wq + bq (split in, split-bf16 out)
  mfma_gemm<1, 1><<<dim3(DPROJ / 128, NROW / 128), blk, 0, stream>>>(
      xh, xl, WqTh, WqTl, bq, nullptr, Qh, Ql, NROW, DPROJ, DIN, 1.0f);
  // 4) K = x @ Wk + bk
  mfma_gemm<1, 1><<<dim3(DPROJ / 128, NROW / 128), blk, 0, stream>>>(
      xh, xl, WkTh, WkTl, bk, nullptr, Kh, Kl, NROW, DPROJ, DIN, 1.0f);

  // 5) scores = (Q @ K^T) / sqrt(32) -> attn_w f32 (overwrites convert scratch)
  mfma_gemm<1, 0><<<dim3(NROW / 128, NROW / 128), blk, 0, stream>>>(
      Qh, Ql, Kh, Kl, nullptr, attn_w, nullptr, nullptr,
      NROW, NROW, DPROJ, INV_DK);

  // 6) softmax in place + P bf16
  softmax_p<<<NROW, blk, 0, stream>>>(attn_w, P);

  // 7) attn_out = P @ V : A=P [4096][4096], B=VT [1024][4096]
  mfma_gemm<0, 0><<<dim3(DPROJ / 128, NROW / 128), blk, 0, stream>>>(
      P, nullptr, VT, nullptr, nullptr, attn_out, nullptr, nullptr,
      NROW, DPROJ, NROW, 1.0f);
}